// Round 1
// baseline (1596.542 us; speedup 1.0000x reference)
//
#include <hip/hip_runtime.h>
#include <hip/hip_bf16.h>
#include <math.h>

#define CHANNELS 64
#define KK 25  // 5x5 kernels

// Broadcast lane i's value of v to all lanes (v_readlane -> SGPR operand in fma).
__device__ __forceinline__ float lane_bcast(float v, int i) {
    return __uint_as_float(__builtin_amdgcn_readlane(__float_as_uint(v), i));
}

// Monotone float -> uint encoding (order-preserving incl. negatives).
__device__ __forceinline__ unsigned int enc_f32(float f) {
    unsigned int u = __float_as_uint(f);
    return (u & 0x80000000u) ? ~u : (u | 0x80000000u);
}
__device__ __forceinline__ float dec_f32(unsigned int e) {
    return __uint_as_float((e & 0x80000000u) ? (e ^ 0x80000000u) : ~e);
}
#define ENC_NEG_INF 0x007FFFFFu  // enc(-inf)

__global__ __launch_bounds__(256) void init_agg(unsigned int* __restrict__ agg, int n) {
    int i = blockIdx.x * 256 + threadIdx.x;
    if (i < n) agg[i] = ENC_NEG_INF;
}

// xk[n, k, o] = sum_i X[n,i] * W[k,i,o]; stored bf16.
// grid: (ceil(N/16), 25); block 256 = 4 waves, each wave does 4 nodes for kernel k.
__global__ __launch_bounds__(256) void gemm_xk(
    const float* __restrict__ X, const float* __restrict__ W,
    __hip_bfloat16* __restrict__ XK, int N)
{
    const int k    = blockIdx.y;
    const int lane = threadIdx.x & 63;
    const int wv   = threadIdx.x >> 6;
    const int n0   = blockIdx.x * 16 + wv * 4;
    if (n0 >= N) return;
    const int m1 = min(n0 + 1, N - 1);
    const int m2 = min(n0 + 2, N - 1);
    const int m3 = min(n0 + 3, N - 1);
    const float* __restrict__ Wk = W + (size_t)k * CHANNELS * CHANNELS;

    // x row for each node lives across the wave's 64 lanes.
    float xv0 = X[(size_t)n0 * CHANNELS + lane];
    float xv1 = X[(size_t)m1 * CHANNELS + lane];
    float xv2 = X[(size_t)m2 * CHANNELS + lane];
    float xv3 = X[(size_t)m3 * CHANNELS + lane];

    float a0 = 0.f, a1 = 0.f, a2 = 0.f, a3 = 0.f;
#pragma unroll
    for (int i = 0; i < CHANNELS; ++i) {
        float w = Wk[i * CHANNELS + lane];
        a0 = fmaf(lane_bcast(xv0, i), w, a0);
        a1 = fmaf(lane_bcast(xv1, i), w, a1);
        a2 = fmaf(lane_bcast(xv2, i), w, a2);
        a3 = fmaf(lane_bcast(xv3, i), w, a3);
    }
    const size_t stride = (size_t)KK * CHANNELS;
    size_t base = (size_t)n0 * stride + (size_t)k * CHANNELS + lane;
    XK[base] = __float2bfloat16(a0);
    if (n0 + 1 < N) XK[base + stride]     = __float2bfloat16(a1);
    if (n0 + 2 < N) XK[base + 2 * stride] = __float2bfloat16(a2);
    if (n0 + 3 < N) XK[base + 3 * stride] = __float2bfloat16(a3);
}

// One wave per edge: bilinear-basis weighted gather of 4 xk rows, scatter-max.
__global__ __launch_bounds__(256) void edge_msg(
    const int* __restrict__ ei, const float* __restrict__ ps,
    const __hip_bfloat16* __restrict__ XK,
    unsigned int* __restrict__ agg, int E)
{
    const int lane = threadIdx.x & 63;
    const int e = (int)((blockIdx.x * 256 + threadIdx.x) >> 6);
    if (e >= E) return;
    const int src = ei[e];
    const int dst = ei[E + e];
    const float v0 = ps[2 * e]     * 4.0f;
    const float v1 = ps[2 * e + 1] * 4.0f;
    const float fb0 = floorf(v0), fb1 = floorf(v1);
    const float f0 = v0 - fb0, f1 = v1 - fb1;
    int b0 = max(min((int)fb0, 4), 0);
    int b1 = max(min((int)fb1, 4), 0);
    int c0 = min(b0 + 1, 4);
    int c1 = min(b1 + 1, 4);

    const __hip_bfloat16* __restrict__ base =
        XK + (size_t)src * (KK * CHANNELS) + lane;
    float x00 = __bfloat162float(base[(b0 + 5 * b1) * CHANNELS]);
    float x10 = __bfloat162float(base[(c0 + 5 * b1) * CHANNELS]);
    float x01 = __bfloat162float(base[(b0 + 5 * c1) * CHANNELS]);
    float x11 = __bfloat162float(base[(c0 + 5 * c1) * CHANNELS]);

    const float w00 = (1.f - f0) * (1.f - f1);
    const float w10 = f0 * (1.f - f1);
    const float w01 = (1.f - f0) * f1;
    const float w11 = f0 * f1;
    float m = w00 * x00 + w10 * x10 + w01 * x01 + w11 * x11;

    atomicMax(&agg[(size_t)dst * CHANNELS + lane], enc_f32(m));
}

// out[n,o] = relu?( decode(agg) + X[n,:]@root[:,o] + bias[o] )
// grid ceil(N/4), block 256 = 4 waves, wave per node.
__global__ __launch_bounds__(256) void finalize_k(
    const unsigned int* __restrict__ agg, const float* __restrict__ X,
    const float* __restrict__ root, const float* __restrict__ bias,
    float* __restrict__ out, int N, int do_relu)
{
    const int lane = threadIdx.x & 63;
    const int n = blockIdx.x * 4 + (threadIdx.x >> 6);
    if (n >= N) return;
    float xv = X[(size_t)n * CHANNELS + lane];
    float acc = 0.f;
#pragma unroll
    for (int i = 0; i < CHANNELS; ++i)
        acc = fmaf(lane_bcast(xv, i), root[i * CHANNELS + lane], acc);
    unsigned int enc = agg[(size_t)n * CHANNELS + lane];
    float a = dec_f32(enc);
    if (!isfinite(a)) a = 0.f;  // empty node (-inf) -> 0, PyG convention
    float r = a + acc + bias[lane];
    if (do_relu) r = fmaxf(r, 0.f);
    out[(size_t)n * CHANNELS + lane] = r;
}

extern "C" void kernel_launch(void* const* d_in, const int* in_sizes, int n_in,
                              void* d_out, int out_size, void* d_ws, size_t ws_size,
                              hipStream_t stream) {
    const float* x     = (const float*)d_in[0];
    const int*   ei    = (const int*)d_in[1];
    const float* ps    = (const float*)d_in[2];
    const float* W1    = (const float*)d_in[3];
    const float* root1 = (const float*)d_in[4];
    const float* bias1 = (const float*)d_in[5];
    const float* W2    = (const float*)d_in[6];
    const float* root2 = (const float*)d_in[7];
    const float* bias2 = (const float*)d_in[8];
    float* out = (float*)d_out;

    const int N = in_sizes[0] / CHANNELS;
    const int E = in_sizes[1] / 2;

    char* ws = (char*)d_ws;
    __hip_bfloat16* xk = (__hip_bfloat16*)ws;                     // N*25*64 bf16 = 160 MB
    size_t xk_bytes = (size_t)N * KK * CHANNELS * sizeof(__hip_bfloat16);
    unsigned int* agg = (unsigned int*)(ws + xk_bytes);           // N*64 u32 = 12.8 MB
    size_t agg_bytes = (size_t)N * CHANNELS * sizeof(unsigned int);
    float* h = (float*)(ws + xk_bytes + agg_bytes);               // N*64 f32 = 12.8 MB

    const int agg_elems = N * CHANNELS;
    dim3 gemm_grid((N + 15) / 16, KK);
    const int edge_blocks = (E + 3) / 4;   // 4 edges (waves) per 256-thread block
    const int fin_blocks  = (N + 3) / 4;
    const int init_blocks = (agg_elems + 255) / 256;

    // ---- layer 1: h = relu(spline_conv(x, W1, root1, bias1)) ----
    init_agg<<<init_blocks, 256, 0, stream>>>(agg, agg_elems);
    gemm_xk<<<gemm_grid, 256, 0, stream>>>(x, W1, xk, N);
    edge_msg<<<edge_blocks, 256, 0, stream>>>(ei, ps, xk, agg, E);
    finalize_k<<<fin_blocks, 256, 0, stream>>>(agg, x, root1, bias1, h, N, 1);

    // ---- layer 2: out = spline_conv(h, W2, root2, bias2) ----
    init_agg<<<init_blocks, 256, 0, stream>>>(agg, agg_elems);
    gemm_xk<<<gemm_grid, 256, 0, stream>>>(h, W2, xk, N);
    edge_msg<<<edge_blocks, 256, 0, stream>>>(ei, ps, xk, agg, E);
    finalize_k<<<fin_blocks, 256, 0, stream>>>(agg, h, root2, bias2, out, N, 0);
}

// Round 2
// 901.250 us; speedup vs baseline: 1.7715x; 1.7715x over previous
//
#include <hip/hip_runtime.h>
#include <hip/hip_bf16.h>
#include <math.h>

#define CHANNELS 64
#define KK 25           // 5x5 kernels
#define NCOL (KK * CHANNELS)   // 1600 output columns of the xk GEMM
#define NTILES (NCOL / 16)     // 100 col-tiles of 16

typedef __attribute__((ext_vector_type(8))) short bf16x8;
typedef __attribute__((ext_vector_type(4))) float f32x4;

// RNE float -> bf16 bits
__device__ __forceinline__ short f2bf(float f) {
    unsigned int u = __float_as_uint(f);
    u = (u + 0x7FFFu + ((u >> 16) & 1u)) >> 16;
    return (short)u;
}

// Monotone float -> uint encoding (order-preserving incl. negatives).
__device__ __forceinline__ unsigned int enc_f32(float f) {
    unsigned int u = __float_as_uint(f);
    return (u & 0x80000000u) ? ~u : (u | 0x80000000u);
}
__device__ __forceinline__ float dec_f32(unsigned int e) {
    return __uint_as_float((e & 0x80000000u) ? (e ^ 0x80000000u) : ~e);
}
#define ENC_NEG_INF 0x007FFFFFu  // enc(-inf)

__device__ __forceinline__ float lane_bcast(float v, int i) {
    return __uint_as_float(__builtin_amdgcn_readlane(__float_as_uint(v), i));
}

__global__ __launch_bounds__(256) void init_agg(unsigned int* __restrict__ agg, int n) {
    int i = blockIdx.x * 256 + threadIdx.x;
    if (i < n) agg[i] = ENC_NEG_INF;
}

// Repack W [25][64][64] fp32 -> Wb bf16 in B-fragment order:
// Wb[((t*2+q)*64 + lane)*8 + j] = B[k = q*32 + (lane>>4)*8 + j][col = t*16 + (lane&15)]
// where B[i][c] = W[c>>6][i][c&63].
__global__ __launch_bounds__(256) void prep_w(const float* __restrict__ W,
                                              __hip_bfloat16* __restrict__ Wb) {
    int idx = blockIdx.x * 256 + threadIdx.x;   // 100*2*64*8 = 102400
    if (idx >= NTILES * 2 * 64 * 8) return;
    int j = idx & 7;
    int l = (idx >> 3) & 63;
    int q = (idx >> 9) & 1;
    int t = idx >> 10;
    int col  = t * 16 + (l & 15);
    int k    = q * 32 + (l >> 4) * 8 + j;
    int kk   = col >> 6;
    int o    = col & 63;
    unsigned short b = (unsigned short)f2bf(W[kk * 4096 + k * 64 + o]);
    ((unsigned short*)Wb)[idx] = b;
}

// MFMA GEMM: XK[n, c] = sum_i X[n,i] * B[i,c],  c = kk*64+o.  XK stored bf16.
// grid: ceil(N/64) blocks of 256 threads; wave wv owns rows [blk*64+wv*16, +16),
// loops over all 100 col-tiles. A fragments loaded once, reused 100x.
__global__ __launch_bounds__(256) void gemm_mfma(
    const float* __restrict__ X, const __hip_bfloat16* __restrict__ Wb,
    __hip_bfloat16* __restrict__ XK, int N)
{
    const int lane = threadIdx.x & 63;
    const int wv   = threadIdx.x >> 6;
    const int rb   = blockIdx.x * 64 + wv * 16;
    const int m    = lane & 15;
    const int quad = lane >> 4;

    // ---- A fragments (two K=32 halves), rows clamped for the ragged tail ----
    const int rowc = min(rb + m, N - 1);
    const float* __restrict__ xp = X + (size_t)rowc * CHANNELS + quad * 8;
    float af[16];
    *(float4*)(af)      = *(const float4*)(xp);
    *(float4*)(af + 4)  = *(const float4*)(xp + 4);
    *(float4*)(af + 8)  = *(const float4*)(xp + 32);
    *(float4*)(af + 12) = *(const float4*)(xp + 36);
    bf16x8 A0, A1;
#pragma unroll
    for (int j = 0; j < 8; ++j) { A0[j] = f2bf(af[j]); A1[j] = f2bf(af[8 + j]); }

    const bf16x8* __restrict__ wb = (const bf16x8*)Wb;
    // store base: lane writes rows rb+quad*4+i, col m (within tile)
    const int r0 = rb + quad * 4;
    __hip_bfloat16* __restrict__ outp = XK + (size_t)r0 * NCOL + m;
    const int rmax = N - r0;   // store row i iff i < rmax

    bf16x8 B0 = wb[lane];
    bf16x8 B1 = wb[64 + lane];
    for (int t = 0; t < NTILES; ++t) {
        bf16x8 nB0, nB1;
        if (t + 1 < NTILES) {
            nB0 = wb[(t + 1) * 128 + lane];
            nB1 = wb[(t + 1) * 128 + 64 + lane];
        }
        f32x4 acc = {0.f, 0.f, 0.f, 0.f};
        acc = __builtin_amdgcn_mfma_f32_16x16x32_bf16(A0, B0, acc, 0, 0, 0);
        acc = __builtin_amdgcn_mfma_f32_16x16x32_bf16(A1, B1, acc, 0, 0, 0);
#pragma unroll
        for (int i = 0; i < 4; ++i) {
            if (i < rmax)
                outp[(size_t)i * NCOL + t * 16] = __float2bfloat16(acc[i]);
        }
        B0 = nB0; B1 = nB1;
    }
}

// One wave per edge: bilinear-basis weighted gather of 4 xk rows, scatter-max.
__global__ __launch_bounds__(256) void edge_msg(
    const int* __restrict__ ei, const float* __restrict__ ps,
    const __hip_bfloat16* __restrict__ XK,
    unsigned int* __restrict__ agg, int E)
{
    const int lane = threadIdx.x & 63;
    const int e = (int)((blockIdx.x * 256 + threadIdx.x) >> 6);
    if (e >= E) return;
    const int src = ei[e];
    const int dst = ei[E + e];
    const float v0 = ps[2 * e]     * 4.0f;
    const float v1 = ps[2 * e + 1] * 4.0f;
    const float fb0 = floorf(v0), fb1 = floorf(v1);
    const float f0 = v0 - fb0, f1 = v1 - fb1;
    int b0 = max(min((int)fb0, 4), 0);
    int b1 = max(min((int)fb1, 4), 0);
    int c0 = min(b0 + 1, 4);
    int c1 = min(b1 + 1, 4);

    const __hip_bfloat16* __restrict__ base =
        XK + (size_t)src * NCOL + lane;
    float x00 = __bfloat162float(base[(b0 + 5 * b1) * CHANNELS]);
    float x10 = __bfloat162float(base[(c0 + 5 * b1) * CHANNELS]);
    float x01 = __bfloat162float(base[(b0 + 5 * c1) * CHANNELS]);
    float x11 = __bfloat162float(base[(c0 + 5 * c1) * CHANNELS]);

    const float w00 = (1.f - f0) * (1.f - f1);
    const float w10 = f0 * (1.f - f1);
    const float w01 = (1.f - f0) * f1;
    const float w11 = f0 * f1;
    float m = w00 * x00 + w10 * x10 + w01 * x01 + w11 * x11;

    atomicMax(&agg[(size_t)dst * CHANNELS + lane], enc_f32(m));
}

// out[n,o] = relu?( decode(agg) + X[n,:]@root[:,o] + bias[o] )
__global__ __launch_bounds__(256) void finalize_k(
    const unsigned int* __restrict__ agg, const float* __restrict__ X,
    const float* __restrict__ root, const float* __restrict__ bias,
    float* __restrict__ out, int N, int do_relu)
{
    const int lane = threadIdx.x & 63;
    const int n = blockIdx.x * 4 + (threadIdx.x >> 6);
    if (n >= N) return;
    float xv = X[(size_t)n * CHANNELS + lane];
    float acc = 0.f;
#pragma unroll
    for (int i = 0; i < CHANNELS; ++i)
        acc = fmaf(lane_bcast(xv, i), root[i * CHANNELS + lane], acc);
    unsigned int enc = agg[(size_t)n * CHANNELS + lane];
    float a = dec_f32(enc);
    if (!isfinite(a)) a = 0.f;  // empty node (-inf) -> 0, PyG convention
    float r = a + acc + bias[lane];
    if (do_relu) r = fmaxf(r, 0.f);
    out[(size_t)n * CHANNELS + lane] = r;
}

extern "C" void kernel_launch(void* const* d_in, const int* in_sizes, int n_in,
                              void* d_out, int out_size, void* d_ws, size_t ws_size,
                              hipStream_t stream) {
    const float* x     = (const float*)d_in[0];
    const int*   ei    = (const int*)d_in[1];
    const float* ps    = (const float*)d_in[2];
    const float* W1    = (const float*)d_in[3];
    const float* root1 = (const float*)d_in[4];
    const float* bias1 = (const float*)d_in[5];
    const float* W2    = (const float*)d_in[6];
    const float* root2 = (const float*)d_in[7];
    const float* bias2 = (const float*)d_in[8];
    float* out = (float*)d_out;

    const int N = in_sizes[0] / CHANNELS;
    const int E = in_sizes[1] / 2;

    char* ws = (char*)d_ws;
    __hip_bfloat16* xk = (__hip_bfloat16*)ws;                     // N*1600 bf16 = 160 MB
    size_t xk_bytes = (size_t)N * NCOL * sizeof(__hip_bfloat16);
    unsigned int* agg = (unsigned int*)(ws + xk_bytes);           // N*64 u32 = 12.8 MB
    size_t agg_bytes = (size_t)N * CHANNELS * sizeof(unsigned int);
    float* h = (float*)(ws + xk_bytes + agg_bytes);               // N*64 f32 = 12.8 MB
    // Wb (200 KB, bf16 fragment-packed W) ALIASES agg: prep+gemm run strictly
    // before init_agg each layer, and nothing reads Wb after gemm completes.
    __hip_bfloat16* Wb = (__hip_bfloat16*)agg;

    const int agg_elems = N * CHANNELS;
    const int prep_blocks = (NTILES * 2 * 64 * 8 + 255) / 256;   // 400
    const int gemm_blocks = (N + 63) / 64;
    const int edge_blocks = (E + 3) / 4;   // 4 edges (waves) per 256-thread block
    const int fin_blocks  = (N + 3) / 4;
    const int init_blocks = (agg_elems + 255) / 256;

    // ---- layer 1: h = relu(spline_conv(x, W1, root1, bias1)) ----
    prep_w<<<prep_blocks, 256, 0, stream>>>(W1, Wb);
    gemm_mfma<<<gemm_blocks, 256, 0, stream>>>(x, Wb, xk, N);
    init_agg<<<init_blocks, 256, 0, stream>>>(agg, agg_elems);   // clobbers Wb (done with it)
    edge_msg<<<edge_blocks, 256, 0, stream>>>(ei, ps, xk, agg, E);
    finalize_k<<<fin_blocks, 256, 0, stream>>>(agg, x, root1, bias1, h, N, 1);

    // ---- layer 2: out = spline_conv(h, W2, root2, bias2) ----
    prep_w<<<prep_blocks, 256, 0, stream>>>(W2, Wb);
    gemm_mfma<<<gemm_blocks, 256, 0, stream>>>(h, Wb, xk, N);
    init_agg<<<init_blocks, 256, 0, stream>>>(agg, agg_elems);
    edge_msg<<<edge_blocks, 256, 0, stream>>>(ei, ps, xk, agg, E);
    finalize_k<<<fin_blocks, 256, 0, stream>>>(agg, h, root2, bias2, out, N, 0);
}

// Round 3
// 696.640 us; speedup vs baseline: 2.2918x; 1.2937x over previous
//
#include <hip/hip_runtime.h>
#include <hip/hip_bf16.h>
#include <math.h>

#define CHANNELS 64
#define KK 25                  // 5x5 kernels
#define NCOL (KK * CHANNELS)   // 1600 output columns of the xk GEMM
#define NTILES (NCOL / 16)     // 100 col-tiles of 16

typedef __attribute__((ext_vector_type(8))) short bf16x8;
typedef __attribute__((ext_vector_type(4))) float f32x4;

// RNE float -> bf16 bits
__device__ __forceinline__ short f2bf(float f) {
    unsigned int u = __float_as_uint(f);
    u = (u + 0x7FFFu + ((u >> 16) & 1u)) >> 16;
    return (short)u;
}

__device__ __forceinline__ float lane_bcast(float v, int i) {
    return __uint_as_float(__builtin_amdgcn_readlane(__float_as_uint(v), i));
}

// ---------------- CSR build: histogram -> scan -> scatter ----------------

__global__ __launch_bounds__(256) void zero_counts(unsigned int* __restrict__ c, int n) {
    int i = blockIdx.x * 256 + threadIdx.x;
    if (i < n) c[i] = 0u;
}

__global__ __launch_bounds__(256) void hist_dst(const int* __restrict__ ei,
                                                unsigned int* __restrict__ counts, int E) {
    int e = blockIdx.x * 256 + threadIdx.x;
    if (e < E) atomicAdd(&counts[ei[E + e]], 1u);
}

// Single-block exclusive scan of counts[0..N) -> cursor[0..N).
// After the scatter kernel bumps cursor, cursor[i] == inclusive prefix == row_end(i).
#define SCAN_BLOCK 1024
__global__ __launch_bounds__(SCAN_BLOCK) void scan_counts(
    const unsigned int* __restrict__ counts, unsigned int* __restrict__ cursor, int N)
{
    __shared__ unsigned int part[SCAN_BLOCK];
    const int t = threadIdx.x;
    const int chunk = (N + SCAN_BLOCK - 1) / SCAN_BLOCK;
    const int lo = t * chunk, hi = min(lo + chunk, N);
    unsigned int s = 0;
    for (int i = lo; i < hi; ++i) s += counts[i];
    part[t] = s;
    __syncthreads();
    for (int off = 1; off < SCAN_BLOCK; off <<= 1) {
        unsigned int v = (t >= off) ? part[t - off] : 0u;
        __syncthreads();
        part[t] += v;
        __syncthreads();
    }
    unsigned int run = (t > 0) ? part[t - 1] : 0u;  // exclusive base of this chunk
    for (int i = lo; i < hi; ++i) {
        cursor[i] = run;
        run += counts[i];
    }
}

// Per-edge record: {src, packed 4x5-bit k-indices, f0, f1} = 16 B.
__global__ __launch_bounds__(256) void scatter_edges(
    const int* __restrict__ ei, const float* __restrict__ ps,
    unsigned int* __restrict__ cursor, int4* __restrict__ sorted, int E)
{
    int e = blockIdx.x * 256 + threadIdx.x;
    if (e >= E) return;
    const int src = ei[e];
    const int dst = ei[E + e];
    const float v0 = ps[2 * e]     * 4.0f;
    const float v1 = ps[2 * e + 1] * 4.0f;
    const float fb0 = floorf(v0), fb1 = floorf(v1);
    const float f0 = v0 - fb0, f1 = v1 - fb1;
    const int b0 = max(min((int)fb0, 4), 0);
    const int b1 = max(min((int)fb1, 4), 0);
    const int c0 = min(b0 + 1, 4);
    const int c1 = min(b1 + 1, 4);
    const unsigned int pk = (unsigned)(b0 + 5 * b1)
                          | ((unsigned)(c0 + 5 * b1) << 5)
                          | ((unsigned)(b0 + 5 * c1) << 10)
                          | ((unsigned)(c0 + 5 * c1) << 15);
    const unsigned int pos = atomicAdd(&cursor[dst], 1u);
    sorted[pos] = make_int4(src, (int)pk, __float_as_int(f0), __float_as_int(f1));
}

// ---------------- xk GEMM (MFMA) ----------------

// Repack W [25][64][64] fp32 -> Wb bf16 in B-fragment order.
__global__ __launch_bounds__(256) void prep_w(const float* __restrict__ W,
                                              __hip_bfloat16* __restrict__ Wb) {
    int idx = blockIdx.x * 256 + threadIdx.x;   // 100*2*64*8 = 102400
    if (idx >= NTILES * 2 * 64 * 8) return;
    int j = idx & 7;
    int l = (idx >> 3) & 63;
    int q = (idx >> 9) & 1;
    int t = idx >> 10;
    int col  = t * 16 + (l & 15);
    int k    = q * 32 + (l >> 4) * 8 + j;
    int kk   = col >> 6;
    int o    = col & 63;
    ((unsigned short*)Wb)[idx] = (unsigned short)f2bf(W[kk * 4096 + k * 64 + o]);
}

// XK[n, c] = sum_i X[n,i] * B[i,c]; stored bf16. Wave owns 16 rows x all tiles.
__global__ __launch_bounds__(256) void gemm_mfma(
    const float* __restrict__ X, const __hip_bfloat16* __restrict__ Wb,
    __hip_bfloat16* __restrict__ XK, int N)
{
    const int lane = threadIdx.x & 63;
    const int wv   = threadIdx.x >> 6;
    const int rb   = blockIdx.x * 64 + wv * 16;
    const int m    = lane & 15;
    const int quad = lane >> 4;

    const int rowc = min(rb + m, N - 1);
    const float* __restrict__ xp = X + (size_t)rowc * CHANNELS + quad * 8;
    float af[16];
    *(float4*)(af)      = *(const float4*)(xp);
    *(float4*)(af + 4)  = *(const float4*)(xp + 4);
    *(float4*)(af + 8)  = *(const float4*)(xp + 32);
    *(float4*)(af + 12) = *(const float4*)(xp + 36);
    bf16x8 A0, A1;
#pragma unroll
    for (int j = 0; j < 8; ++j) { A0[j] = f2bf(af[j]); A1[j] = f2bf(af[8 + j]); }

    const bf16x8* __restrict__ wb = (const bf16x8*)Wb;
    const int r0 = rb + quad * 4;
    __hip_bfloat16* __restrict__ outp = XK + (size_t)r0 * NCOL + m;
    const int rmax = N - r0;

    bf16x8 B0 = wb[lane];
    bf16x8 B1 = wb[64 + lane];
    for (int t = 0; t < NTILES; ++t) {
        bf16x8 nB0, nB1;
        if (t + 1 < NTILES) {
            nB0 = wb[(t + 1) * 128 + lane];
            nB1 = wb[(t + 1) * 128 + 64 + lane];
        }
        f32x4 acc = {0.f, 0.f, 0.f, 0.f};
        acc = __builtin_amdgcn_mfma_f32_16x16x32_bf16(A0, B0, acc, 0, 0, 0);
        acc = __builtin_amdgcn_mfma_f32_16x16x32_bf16(A1, B1, acc, 0, 0, 0);
#pragma unroll
        for (int i = 0; i < 4; ++i) {
            if (i < rmax)
                outp[(size_t)i * NCOL + t * 16] = __float2bfloat16(acc[i]);
        }
        B0 = nB0; B1 = nB1;
    }
}

// ---------------- fused aggregate (segment-max) + root + bias (+relu) ----------------
// One wave per dst node; edges contiguous in sorted[]; no atomics; one write/node.
__global__ __launch_bounds__(256) void agg_node(
    const int4* __restrict__ sorted, const unsigned int* __restrict__ cursor,
    const __hip_bfloat16* __restrict__ XK, const float* __restrict__ X,
    const float* __restrict__ root, const float* __restrict__ bias,
    float* __restrict__ out, int N, int do_relu)
{
    const int lane = threadIdx.x & 63;
    const int n = blockIdx.x * 4 + (threadIdx.x >> 6);
    if (n >= N) return;
    // after scatter, cursor[i] == row_end(i); row_begin(i) == cursor[i-1] (0 for i=0)
    const int beg = (n > 0) ? (int)cursor[n - 1] : 0;
    const int end = (int)cursor[n];

    float m = -INFINITY;
    if (beg < end) {
        int4 r = sorted[beg];
        for (int e = beg; e < end; ++e) {
            int4 rn = r;
            if (e + 1 < end) rn = sorted[e + 1];   // prefetch next record
            const int src = r.x;
            const unsigned int pk = (unsigned int)r.y;
            const float f0 = __int_as_float(r.z);
            const float f1 = __int_as_float(r.w);
            const __hip_bfloat16* __restrict__ base = XK + (size_t)src * NCOL + lane;
            const float x00 = __bfloat162float(base[(pk & 31) * CHANNELS]);
            const float x10 = __bfloat162float(base[((pk >> 5) & 31) * CHANNELS]);
            const float x01 = __bfloat162float(base[((pk >> 10) & 31) * CHANNELS]);
            const float x11 = __bfloat162float(base[((pk >> 15) & 31) * CHANNELS]);
            const float w00 = (1.f - f0) * (1.f - f1);
            const float w10 = f0 * (1.f - f1);
            const float w01 = (1.f - f0) * f1;
            const float w11 = f0 * f1;
            m = fmaxf(m, (x00 * w00 + x10 * w10) + (x01 * w01 + x11 * w11));
            r = rn;
        }
    }
    float a = isfinite(m) ? m : 0.f;   // empty node -> 0 (PyG convention)

    float xv = X[(size_t)n * CHANNELS + lane];
    float acc = 0.f;
#pragma unroll
    for (int i = 0; i < CHANNELS; ++i)
        acc = fmaf(lane_bcast(xv, i), root[i * CHANNELS + lane], acc);

    float res = a + acc + bias[lane];
    if (do_relu) res = fmaxf(res, 0.f);
    out[(size_t)n * CHANNELS + lane] = res;
}

extern "C" void kernel_launch(void* const* d_in, const int* in_sizes, int n_in,
                              void* d_out, int out_size, void* d_ws, size_t ws_size,
                              hipStream_t stream) {
    const float* x     = (const float*)d_in[0];
    const int*   ei    = (const int*)d_in[1];
    const float* ps    = (const float*)d_in[2];
    const float* W1    = (const float*)d_in[3];
    const float* root1 = (const float*)d_in[4];
    const float* bias1 = (const float*)d_in[5];
    const float* W2    = (const float*)d_in[6];
    const float* root2 = (const float*)d_in[7];
    const float* bias2 = (const float*)d_in[8];
    float* out = (float*)d_out;

    const int N = in_sizes[0] / CHANNELS;
    const int E = in_sizes[1] / 2;

    // ---- workspace layout (~198.8 MB) ----
    char* ws = (char*)d_ws;
    __hip_bfloat16* xk = (__hip_bfloat16*)ws;                       // N*1600*2 = 160 MB
    size_t off = (size_t)N * NCOL * sizeof(__hip_bfloat16);
    float* h = (float*)(ws + off);                                  // N*64*4 = 12.8 MB
    off += (size_t)N * CHANNELS * sizeof(float);
    int4* sorted = (int4*)(ws + off);                               // E*16 = 25.6 MB
    off += (size_t)E * sizeof(int4);
    unsigned int* counts = (unsigned int*)(ws + off);               // max(N*4, Wb 204800 B)
    __hip_bfloat16* Wb = (__hip_bfloat16*)counts;                   // aliases counts (dead after scan)
    off += ((size_t)N * 4 > 204800 ? (size_t)N * 4 : 204800);
    unsigned int* cursor = (unsigned int*)(ws + off);               // N*4

    const int prep_blocks = (NTILES * 2 * 64 * 8 + 255) / 256;
    const int gemm_blocks = (N + 63) / 64;
    const int node_blocks = (N + 3) / 4;
    const int edgeT_blocks = (E + 255) / 256;
    const int nT_blocks = (N + 255) / 256;

    // ---- CSR build (once; shared by both layers) ----
    zero_counts<<<nT_blocks, 256, 0, stream>>>(counts, N);
    hist_dst<<<edgeT_blocks, 256, 0, stream>>>(ei, counts, E);
    scan_counts<<<1, SCAN_BLOCK, 0, stream>>>(counts, cursor, N);
    scatter_edges<<<edgeT_blocks, 256, 0, stream>>>(ei, ps, cursor, sorted, E);

    // ---- layer 1: h = relu(spline_conv(x, W1, root1, bias1)) ----
    prep_w<<<prep_blocks, 256, 0, stream>>>(W1, Wb);   // clobbers counts (dead)
    gemm_mfma<<<gemm_blocks, 256, 0, stream>>>(x, Wb, xk, N);
    agg_node<<<node_blocks, 256, 0, stream>>>(sorted, cursor, xk, x, root1, bias1, h, N, 1);

    // ---- layer 2: out = spline_conv(h, W2, root2, bias2) ----
    prep_w<<<prep_blocks, 256, 0, stream>>>(W2, Wb);
    gemm_mfma<<<gemm_blocks, 256, 0, stream>>>(h, Wb, xk, N);
    agg_node<<<node_blocks, 256, 0, stream>>>(sorted, cursor, xk, h, root2, bias2, out, N, 0);
}

// Round 4
// 594.238 us; speedup vs baseline: 2.6867x; 1.1723x over previous
//
#include <hip/hip_runtime.h>
#include <hip/hip_bf16.h>
#include <math.h>

#define CHANNELS 64
#define KK 25                   // 5x5 kernels
#define NBLK 26                 // 25 spline kernels + 1 root block
#define NCOL (NBLK * CHANNELS)  // 1664 columns of the fused GEMM
#define NTILES (NCOL / 16)      // 104 col-tiles of 16
#define ROWB (NCOL * 2)         // 3328 bytes per xk row

typedef __attribute__((ext_vector_type(8))) short bf16x8;
typedef __attribute__((ext_vector_type(4))) float f32x4;

// RNE float -> bf16 bits
__device__ __forceinline__ short f2bf(float f) {
    unsigned int u = __float_as_uint(f);
    u = (u + 0x7FFFu + ((u >> 16) & 1u)) >> 16;
    return (short)u;
}
// unpack packed bf16 pair (u32) -> floats
__device__ __forceinline__ float blo(unsigned int u) { return __uint_as_float(u << 16); }
__device__ __forceinline__ float bhi(unsigned int u) { return __uint_as_float(u & 0xffff0000u); }

// ---------------- CSR build: histogram -> parallel scan -> scatter ----------------

__global__ __launch_bounds__(256) void zero_counts(unsigned int* __restrict__ c, int n) {
    int i = blockIdx.x * 256 + threadIdx.x;
    if (i < n) c[i] = 0u;
}

__global__ __launch_bounds__(256) void hist_dst(const int* __restrict__ ei,
                                                unsigned int* __restrict__ counts, int E) {
    int e = blockIdx.x * 256 + threadIdx.x;
    if (e < E) atomicAdd(&counts[ei[E + e]], 1u);
}

// A: per-block (1024 items) sums
__global__ __launch_bounds__(256) void scan_a(const unsigned int* __restrict__ counts,
                                              unsigned int* __restrict__ bsum, int N) {
    const int t = threadIdx.x;
    const int base = blockIdx.x * 1024 + t * 4;
    uint4 v = make_uint4(0, 0, 0, 0);
    if (base + 3 < N) v = *(const uint4*)(counts + base);
    else {
        if (base < N)     v.x = counts[base];
        if (base + 1 < N) v.y = counts[base + 1];
        if (base + 2 < N) v.z = counts[base + 2];
    }
    unsigned int s = v.x + v.y + v.z + v.w;
    for (int off = 32; off; off >>= 1) s += __shfl_down(s, off, 64);
    __shared__ unsigned int red[4];
    if ((t & 63) == 0) red[t >> 6] = s;
    __syncthreads();
    if (t == 0) bsum[blockIdx.x] = red[0] + red[1] + red[2] + red[3];
}

// B: single-wave exclusive scan of bsum[nb] (any nb, 64 at a time)
__global__ __launch_bounds__(64) void scan_b(unsigned int* __restrict__ bsum, int nb) {
    const int lane = threadIdx.x;
    unsigned int run = 0;
    for (int base = 0; base < nb; base += 64) {
        unsigned int v = (base + lane < nb) ? bsum[base + lane] : 0u;
        const unsigned int orig = v;
        for (int off = 1; off < 64; off <<= 1) {
            unsigned int u = __shfl_up(v, off, 64);
            if (lane >= off) v += u;
        }
        if (base + lane < nb) bsum[base + lane] = run + v - orig;
        run += __shfl(v, 63, 64);
    }
}

// C: per-block exclusive scan + block offset -> cursor (exclusive prefix)
__global__ __launch_bounds__(256) void scan_c(const unsigned int* __restrict__ counts,
                                              const unsigned int* __restrict__ bsum,
                                              unsigned int* __restrict__ cursor, int N) {
    const int t = threadIdx.x;
    const int base = blockIdx.x * 1024 + t * 4;
    uint4 v = make_uint4(0, 0, 0, 0);
    if (base + 3 < N) v = *(const uint4*)(counts + base);
    else {
        if (base < N)     v.x = counts[base];
        if (base + 1 < N) v.y = counts[base + 1];
        if (base + 2 < N) v.z = counts[base + 2];
    }
    __shared__ unsigned int ps[256];
    ps[t] = v.x + v.y + v.z + v.w;
    __syncthreads();
    for (int off = 1; off < 256; off <<= 1) {
        unsigned int u = (t >= off) ? ps[t - off] : 0u;
        __syncthreads();
        ps[t] += u;
        __syncthreads();
    }
    unsigned int ex = ((t > 0) ? ps[t - 1] : 0u) + bsum[blockIdx.x];
    if (base < N)     cursor[base]     = ex;
    if (base + 1 < N) cursor[base + 1] = ex + v.x;
    if (base + 2 < N) cursor[base + 2] = ex + v.x + v.y;
    if (base + 3 < N) cursor[base + 3] = ex + v.x + v.y + v.z;
}

// Per-edge record: {src, packed 4x5-bit k-indices, f0, f1} = 16 B.
__global__ __launch_bounds__(256) void scatter_edges(
    const int* __restrict__ ei, const float* __restrict__ ps,
    unsigned int* __restrict__ cursor, int4* __restrict__ sorted, int E)
{
    int e = blockIdx.x * 256 + threadIdx.x;
    if (e >= E) return;
    const int src = ei[e];
    const int dst = ei[E + e];
    const float v0 = ps[2 * e]     * 4.0f;
    const float v1 = ps[2 * e + 1] * 4.0f;
    const float fb0 = floorf(v0), fb1 = floorf(v1);
    const float f0 = v0 - fb0, f1 = v1 - fb1;
    const int b0 = max(min((int)fb0, 4), 0);
    const int b1 = max(min((int)fb1, 4), 0);
    const int c0 = min(b0 + 1, 4);
    const int c1 = min(b1 + 1, 4);
    const unsigned int pk = (unsigned)(b0 + 5 * b1)
                          | ((unsigned)(c0 + 5 * b1) << 5)
                          | ((unsigned)(b0 + 5 * c1) << 10)
                          | ((unsigned)(c0 + 5 * c1) << 15);
    const unsigned int pos = atomicAdd(&cursor[dst], 1u);
    sorted[pos] = make_int4(src, (int)pk, __float_as_int(f0), __float_as_int(f1));
}

// ---------------- fused xk GEMM (MFMA): 25 spline kernels + root block ----------------

// Repack [W | root] fp32 -> Wb bf16 in B-fragment order.
__global__ __launch_bounds__(256) void prep_w(const float* __restrict__ W,
                                              const float* __restrict__ root,
                                              __hip_bfloat16* __restrict__ Wb) {
    int idx = blockIdx.x * 256 + threadIdx.x;   // 104*2*64*8 = 106496
    if (idx >= NTILES * 2 * 64 * 8) return;
    int j = idx & 7;
    int l = (idx >> 3) & 63;
    int q = (idx >> 9) & 1;
    int t = idx >> 10;
    int col  = t * 16 + (l & 15);
    int k    = q * 32 + (l >> 4) * 8 + j;
    int kk   = col >> 6;
    int o    = col & 63;
    float src = (kk < KK) ? W[kk * 4096 + k * 64 + o] : root[k * 64 + o];
    ((unsigned short*)Wb)[idx] = (unsigned short)f2bf(src);
}

// XK[n, c] = sum_i X[n,i] * B[i,c]; stored bf16. Wave owns 16 rows x all 104 tiles.
__global__ __launch_bounds__(256) void gemm_mfma(
    const float* __restrict__ X, const __hip_bfloat16* __restrict__ Wb,
    __hip_bfloat16* __restrict__ XK, int N)
{
    const int lane = threadIdx.x & 63;
    const int wv   = threadIdx.x >> 6;
    const int rb   = blockIdx.x * 64 + wv * 16;
    const int m    = lane & 15;
    const int quad = lane >> 4;

    const int rowc = min(rb + m, N - 1);
    const float* __restrict__ xp = X + (size_t)rowc * CHANNELS + quad * 8;
    float af[16];
    *(float4*)(af)      = *(const float4*)(xp);
    *(float4*)(af + 4)  = *(const float4*)(xp + 4);
    *(float4*)(af + 8)  = *(const float4*)(xp + 32);
    *(float4*)(af + 12) = *(const float4*)(xp + 36);
    bf16x8 A0, A1;
#pragma unroll
    for (int j = 0; j < 8; ++j) { A0[j] = f2bf(af[j]); A1[j] = f2bf(af[8 + j]); }

    const bf16x8* __restrict__ wb = (const bf16x8*)Wb;
    const int r0 = rb + quad * 4;
    __hip_bfloat16* __restrict__ outp = XK + (size_t)r0 * NCOL + m;
    const int rmax = N - r0;

    bf16x8 B0 = wb[lane];
    bf16x8 B1 = wb[64 + lane];
    for (int t = 0; t < NTILES; ++t) {
        bf16x8 nB0 = B0, nB1 = B1;
        if (t + 1 < NTILES) {
            nB0 = wb[(t + 1) * 128 + lane];
            nB1 = wb[(t + 1) * 128 + 64 + lane];
        }
        f32x4 acc = {0.f, 0.f, 0.f, 0.f};
        acc = __builtin_amdgcn_mfma_f32_16x16x32_bf16(A0, B0, acc, 0, 0, 0);
        acc = __builtin_amdgcn_mfma_f32_16x16x32_bf16(A1, B1, acc, 0, 0, 0);
#pragma unroll
        for (int i = 0; i < 4; ++i) {
            if (i < rmax)
                outp[(size_t)i * NCOL + t * 16] = __float2bfloat16(acc[i]);
        }
        B0 = nB0; B1 = nB1;
    }
}

// ------------- fused segment-max + root + bias (+relu): 4 edges / wave-iter -------------
// Wave per dst node. Lane = (quarter q, sublane j): handles channels 4j..4j+3 of
// edge beg+4i+q (clamped; duplicates are free under max). dwordx2 bf16 gathers.
__global__ __launch_bounds__(256) void agg_node(
    const int4* __restrict__ sorted, const unsigned int* __restrict__ cursor,
    const __hip_bfloat16* __restrict__ XK, const float* __restrict__ bias,
    float* __restrict__ out, int N, int do_relu)
{
    const int lane = threadIdx.x & 63;
    const int n = blockIdx.x * 4 + (threadIdx.x >> 6);
    if (n >= N) return;
    const int q = lane >> 4, j = lane & 15;
    const int beg = (n > 0) ? (int)cursor[n - 1] : 0;
    const int end = (int)cursor[n];

    float m0 = -INFINITY, m1 = -INFINITY, m2 = -INFINITY, m3 = -INFINITY;
    if (beg < end) {
        int4 r = sorted[min(beg + q, end - 1)];
        for (int i = beg; i < end; i += 4) {
            int4 rn = r;
            if (i + 4 < end) rn = sorted[min(i + 4 + q, end - 1)];  // prefetch
            const unsigned int pk = (unsigned int)r.y;
            const float f0 = __int_as_float(r.z);
            const float f1 = __int_as_float(r.w);
            const char* __restrict__ base =
                (const char*)XK + (size_t)(unsigned)r.x * ROWB + (j << 3);
            const uint2 g0 = *(const uint2*)(base + ((pk & 31) << 7));
            const uint2 g1 = *(const uint2*)(base + (((pk >> 5) & 31) << 7));
            const uint2 g2 = *(const uint2*)(base + (((pk >> 10) & 31) << 7));
            const uint2 g3 = *(const uint2*)(base + (((pk >> 15) & 31) << 7));
            const float w00 = (1.f - f0) * (1.f - f1);
            const float w10 = f0 * (1.f - f1);
            const float w01 = (1.f - f0) * f1;
            const float w11 = f0 * f1;
            float v0 = fmaf(blo(g3.x), w11, fmaf(blo(g2.x), w01, fmaf(blo(g1.x), w10, blo(g0.x) * w00)));
            float v1 = fmaf(bhi(g3.x), w11, fmaf(bhi(g2.x), w01, fmaf(bhi(g1.x), w10, bhi(g0.x) * w00)));
            float v2 = fmaf(blo(g3.y), w11, fmaf(blo(g2.y), w01, fmaf(blo(g1.y), w10, blo(g0.y) * w00)));
            float v3 = fmaf(bhi(g3.y), w11, fmaf(bhi(g2.y), w01, fmaf(bhi(g1.y), w10, bhi(g0.y) * w00)));
            m0 = fmaxf(m0, v0); m1 = fmaxf(m1, v1);
            m2 = fmaxf(m2, v2); m3 = fmaxf(m3, v3);
            r = rn;
        }
    }
    // combine the 4 quarters (each saw a different edge subset)
    m0 = fmaxf(m0, __shfl_xor(m0, 16, 64)); m0 = fmaxf(m0, __shfl_xor(m0, 32, 64));
    m1 = fmaxf(m1, __shfl_xor(m1, 16, 64)); m1 = fmaxf(m1, __shfl_xor(m1, 32, 64));
    m2 = fmaxf(m2, __shfl_xor(m2, 16, 64)); m2 = fmaxf(m2, __shfl_xor(m2, 32, 64));
    m3 = fmaxf(m3, __shfl_xor(m3, 16, 64)); m3 = fmaxf(m3, __shfl_xor(m3, 32, 64));
    const float a0 = isfinite(m0) ? m0 : 0.f;
    const float a1 = isfinite(m1) ? m1 : 0.f;
    const float a2 = isfinite(m2) ? m2 : 0.f;
    const float a3 = isfinite(m3) ? m3 : 0.f;

    // root term = xk block 25 (x@root), bias, relu
    const uint2 rt = *(const uint2*)((const char*)XK + (size_t)(unsigned)n * ROWB
                                     + KK * 128 + (j << 3));
    const float4 bv = *(const float4*)(bias + 4 * j);
    float r0 = a0 + blo(rt.x) + bv.x;
    float r1 = a1 + bhi(rt.x) + bv.y;
    float r2 = a2 + blo(rt.y) + bv.z;
    float r3 = a3 + bhi(rt.y) + bv.w;
    if (do_relu) {
        r0 = fmaxf(r0, 0.f); r1 = fmaxf(r1, 0.f);
        r2 = fmaxf(r2, 0.f); r3 = fmaxf(r3, 0.f);
    }
    if (q == 0)
        *(float4*)(out + (size_t)n * CHANNELS + 4 * j) = make_float4(r0, r1, r2, r3);
}

extern "C" void kernel_launch(void* const* d_in, const int* in_sizes, int n_in,
                              void* d_out, int out_size, void* d_ws, size_t ws_size,
                              hipStream_t stream) {
    const float* x     = (const float*)d_in[0];
    const int*   ei    = (const int*)d_in[1];
    const float* ps    = (const float*)d_in[2];
    const float* W1    = (const float*)d_in[3];
    const float* root1 = (const float*)d_in[4];
    const float* bias1 = (const float*)d_in[5];
    const float* W2    = (const float*)d_in[6];
    const float* root2 = (const float*)d_in[7];
    const float* bias2 = (const float*)d_in[8];
    float* out = (float*)d_out;

    const int N = in_sizes[0] / CHANNELS;
    const int E = in_sizes[1] / 2;

    // ---- workspace layout (~205 MB) ----
    char* ws = (char*)d_ws;
    __hip_bfloat16* xk = (__hip_bfloat16*)ws;                       // N*1664*2 = 166.4 MB
    size_t off = (size_t)N * NCOL * sizeof(__hip_bfloat16);
    float* h = (float*)(ws + off);                                  // N*64*4 = 12.8 MB
    off += (size_t)N * CHANNELS * sizeof(float);
    int4* sorted = (int4*)(ws + off);                               // E*16 = 25.6 MB
    off += (size_t)E * sizeof(int4);
    const size_t wb_bytes = (size_t)NTILES * 2 * 64 * 8 * 2;        // 212992
    unsigned int* counts = (unsigned int*)(ws + off);               // max(N*4, wb)
    __hip_bfloat16* Wb = (__hip_bfloat16*)counts;                   // aliases counts (dead after scan)
    off += ((size_t)N * 4 > wb_bytes ? (size_t)N * 4 : wb_bytes);
    unsigned int* cursor = (unsigned int*)(ws + off);               // N*4
    off += (size_t)N * 4;
    unsigned int* bsum = (unsigned int*)(ws + off);                 // ≤4 KB

    const int prep_blocks = (NTILES * 2 * 64 * 8 + 255) / 256;
    const int gemm_blocks = (N + 63) / 64;
    const int node_blocks = (N + 3) / 4;
    const int edgeT_blocks = (E + 255) / 256;
    const int nT_blocks = (N + 255) / 256;
    const int scan_blocks = (N + 1023) / 1024;

    // ---- CSR build (once; shared by both layers) ----
    zero_counts<<<nT_blocks, 256, 0, stream>>>(counts, N);
    hist_dst<<<edgeT_blocks, 256, 0, stream>>>(ei, counts, E);
    scan_a<<<scan_blocks, 256, 0, stream>>>(counts, bsum, N);
    scan_b<<<1, 64, 0, stream>>>(bsum, scan_blocks);
    scan_c<<<scan_blocks, 256, 0, stream>>>(counts, bsum, cursor, N);
    scatter_edges<<<edgeT_blocks, 256, 0, stream>>>(ei, ps, cursor, sorted, E);

    // ---- layer 1: h = relu(spline_conv(x, W1, root1, bias1)) ----
    prep_w<<<prep_blocks, 256, 0, stream>>>(W1, root1, Wb);   // clobbers counts (dead)
    gemm_mfma<<<gemm_blocks, 256, 0, stream>>>(x, Wb, xk, N);
    agg_node<<<node_blocks, 256, 0, stream>>>(sorted, cursor, xk, bias1, h, N, 1);

    // ---- layer 2: out = spline_conv(h, W2, root2, bias2) ----
    prep_w<<<prep_blocks, 256, 0, stream>>>(W2, root2, Wb);
    gemm_mfma<<<gemm_blocks, 256, 0, stream>>>(h, Wb, xk, N);
    agg_node<<<node_blocks, 256, 0, stream>>>(sorted, cursor, xk, bias2, out, N, 0);
}